// Round 5
// baseline (2783.026 us; speedup 1.0000x reference)
//
#include <hip/hip_runtime.h>
#include <hip/hip_bf16.h>

#define Bv 32
#define Tv 512
#define Iv 512
#define Hv 1024
#define NG 4096  // 4*H

typedef short bf16x8 __attribute__((ext_vector_type(8)));   // 8 bf16 held as i16 (guide §3)
typedef float floatx16 __attribute__((ext_vector_type(16)));
typedef unsigned short u16;
typedef unsigned int u32;
typedef unsigned long long u64;
typedef u32 u32x4 __attribute__((ext_vector_type(4)));

__device__ __forceinline__ u16 f2bf(float f) {
  __hip_bfloat16 h = __float2bfloat16(f);
  return *reinterpret_cast<u16*>(&h);
}

__device__ __forceinline__ floatx16 mfma32(bf16x8 a, bf16x8 b, floatx16 c) {
  return __builtin_amdgcn_mfma_f32_32x32x16_bf16(a, b, c, 0, 0, 0);
}

// relaxed agent-scope store: lowers to global_store sc1 (LLC-direct, bypasses
// the non-coherent per-XCD L2). Tagged word = (epoch<<16)|bf16 is atomic.
__device__ __forceinline__ void st_agent_u32(u32* p, u32 v) {
  __hip_atomic_store(p, v, __ATOMIC_RELAXED, __HIP_MEMORY_SCOPE_AGENT);
}

// raw sc1 16B load (LLC-direct). asm volatile => re-issued every retry; the
// consumer must s_waitcnt vmcnt(N) + sched_barrier(0) before reading results
// (rule #18: compiler doesn't know the asm contains a load).
__device__ __forceinline__ u32x4 ld16_sc1(const u32x4* p) {
  u32x4 d;
  asm volatile("global_load_dwordx4 %0, %1, off sc1" : "=v"(d) : "v"(p) : "memory");
  return d;
}

__device__ __forceinline__ u32 permb(u32 a, u32 b, u32 sel) {
  return __builtin_amdgcn_perm(a, b, sel);
}

// ---------------- init: zero hA double buffer (2 x 128KB) + 4KB pad => tag 0
__global__ void k_init(unsigned int* p, int n) {
  int i = blockIdx.x * blockDim.x + threadIdx.x;
  if (i < n) p[i] = 0u;
}

// ---------------- elementwise fp32 -> bf16
__global__ void k_f2bf(const float* __restrict__ in, u16* __restrict__ out, int n) {
  int i = blockIdx.x * blockDim.x + threadIdx.x;
  if (i < n) out[i] = f2bf(in[i]);
}

// ---------------- gather Wh into B-fragment layout: WhF[bl(64)][nt(2)][kt(64)][lane(64)][8]
__global__ void k_whf(const float* __restrict__ Wh, u16* __restrict__ whf) {
  int tid = blockIdx.x * 256 + threadIdx.x;   // 2048*256 = 524288
  int lane = tid & 63;
  int kt   = (tid >> 6) & 63;
  int nt   = (tid >> 12) & 1;
  int bl   = tid >> 13;
  int r    = nt * 32 + (lane & 31);
  int gate = r >> 4, du = r & 15;
  int row  = gate * Hv + bl * 16 + du;
  int k0   = kt * 16 + (lane >> 5) * 8;
  const float* s = Wh + (size_t)row * Hv + k0;
  u16* d = whf + (size_t)tid * 8;
#pragma unroll
  for (int j = 0; j < 8; ++j) d[j] = f2bf(s[j]);
}

// ---------------- xg GEMM (unchanged)
__global__ __launch_bounds__(256) void k_xg(const u16* __restrict__ xb, const u16* __restrict__ wxb,
                                            const float* __restrict__ bx, const float* __restrict__ bh,
                                            float* __restrict__ xg, int t0, int tcshift) {
  __shared__ u16 Al[128 * 40];
  __shared__ u16 Bl[128 * 40];
  int tid = threadIdx.x;
  int wave = tid >> 6, lane = tid & 63;
  int wm = wave & 1, wn = wave >> 1;
  int bm = blockIdx.x, bn = blockIdx.y;
  int Tc = 1 << tcshift;

  floatx16 acc[2][2];
#pragma unroll
  for (int a = 0; a < 2; ++a)
#pragma unroll
    for (int c = 0; c < 2; ++c)
#pragma unroll
      for (int r = 0; r < 16; ++r) acc[a][c][r] = 0.f;

  int lr = tid >> 1;
  int lk = (tid & 1) * 16;
  int m  = bm * 128 + lr;
  int b  = m >> tcshift;
  int tl = m & (Tc - 1);
  const u16* asrc = xb + (size_t)(b * Tv + t0 + tl) * Iv + lk;
  int nrow = bn * 128 + lr;
  const u16* bsrc = wxb + (size_t)nrow * Iv + lk;
  u16* adst = &Al[lr * 40 + lk];
  u16* bdst = &Bl[lr * 40 + lk];

  for (int k0 = 0; k0 < Iv; k0 += 32) {
    __syncthreads();
    *(uint4*)adst       = *(const uint4*)(asrc);
    *(uint4*)(adst + 8) = *(const uint4*)(asrc + 8);
    *(uint4*)bdst       = *(const uint4*)(bsrc);
    *(uint4*)(bdst + 8) = *(const uint4*)(bsrc + 8);
    asrc += 32; bsrc += 32;
    __syncthreads();
#pragma unroll
    for (int kt = 0; kt < 2; ++kt) {
      int ko = kt * 16 + (lane >> 5) * 8;
      bf16x8 a0 = *(const bf16x8*)(&Al[(wm * 64 +      (lane & 31)) * 40 + ko]);
      bf16x8 a1 = *(const bf16x8*)(&Al[(wm * 64 + 32 + (lane & 31)) * 40 + ko]);
      bf16x8 b0 = *(const bf16x8*)(&Bl[(wn * 64 +      (lane & 31)) * 40 + ko]);
      bf16x8 b1 = *(const bf16x8*)(&Bl[(wn * 64 + 32 + (lane & 31)) * 40 + ko]);
      acc[0][0] = mfma32(a0, b0, acc[0][0]);
      acc[0][1] = mfma32(a0, b1, acc[0][1]);
      acc[1][0] = mfma32(a1, b0, acc[1][0]);
      acc[1][1] = mfma32(a1, b1, acc[1][1]);
    }
  }
#pragma unroll
  for (int mt = 0; mt < 2; ++mt) {
#pragma unroll
    for (int ntt = 0; ntt < 2; ++ntt) {
      int nGl = bn * 128 + wn * 64 + ntt * 32 + (lane & 31);
      float bias = bx[nGl] + bh[nGl];
#pragma unroll
      for (int r = 0; r < 16; ++r) {
        int mrow = (r & 3) + 8 * (r >> 2) + 4 * (lane >> 5);
        int mG = bm * 128 + wm * 64 + mt * 32 + mrow;
        int bb = mG >> tcshift;
        int tt = mG & (Tc - 1);
        xg[((size_t)(tt * Bv + bb) << 12) + nGl] = acc[mt][ntt][r] + bias;
      }
    }
  }
}

// ---------------- persistent scan: 64 blocks x 256 thr
// Epoch-tagged h exchange: hA holds u32 words = (tag<<16)|bf16(h), tag = step
// index the word is INPUT for. Producer: fire-and-forget tagged sc1 stores
// (no drain, no barrier, no flag). Consumer: sc1 loads + in-register tag
// validation; stale group => reload. One __syncthreads (S1) per step.
// Safety:
//  - RAW/freshness: per-word atomic tag check (tag t vs stale t-2) replaces
//    flags; torn reads impossible (aligned u32).
//  - WAR: B stores tag t+1 only after S1(t), i.e. after all 4 waves validated
//    tag-t data from ALL 64 blocks; a block's tag-t store happens after its
//    own reads of tag t-1 => causally, overwrites of parity buffer p (tag t+1)
//    occur after every block finished reading p's tag t-1 contents.
//  - red LDS parity-doubled; reads(t) < S1(t+1) < writes(t+2) via the single
//    per-step barrier.
//  - liveness: a retrying wave's producers stored its expected tag before any
//    block can advance past it (transitive chain) => retry terminates.
__global__ __launch_bounds__(256, 1) void k_scan(const u16* __restrict__ whf, const float* __restrict__ xg,
                                                 u32* __restrict__ hAv, float* __restrict__ cbuf,
                                                 float* __restrict__ out, int t0, int Tc) {
  __shared__ float red[2][4][64][36];      // [parity][kh][gate-row][batch], 73728 B
  __shared__ float obuf[16][2][16][16];    // [ts][b2][eb][eu] out stash, 32768 B
  int tid = threadIdx.x;
  int bl = blockIdx.x;                  // 0..63, owns units u0..u0+15
  int kh = tid >> 6, lane = tid & 63;   // wave = k-quarter
  int eu = tid & 15, eb = tid >> 4;     // epilogue: unit-in-block, batch 0..15 (+16)
  int u0 = bl * 16;

  // preload weights into registers, once: w0/w1 = nt0/nt1 fragments for kt=kh*16+kk
  bf16x8 w0[16], w1[16];
  {
    const u16* wb0 = whf + ((size_t)(bl * 2 + 0) << 15);
    const u16* wb1 = whf + ((size_t)(bl * 2 + 1) << 15);
#pragma unroll
    for (int kk = 0; kk < 16; ++kk) {
      int kt = kh * 16 + kk;
      w0[kk] = *(const bf16x8*)(wb0 + (size_t)((kt << 6) + lane) * 8);
      w1[kk] = *(const bf16x8*)(wb1 + (size_t)((kt << 6) + lane) * 8);
    }
  }

  float c0, c1;
  if (t0 == 0) { c0 = 0.f; c1 = 0.f; }
  else {
    c0 = cbuf[eb * Hv + u0 + eu];
    c1 = cbuf[(eb + 16) * Hv + u0 + eu];
  }

  // xg prefetch for tl=0
  float xgv[4][2];
#pragma unroll
  for (int g = 0; g < 4; ++g)
#pragma unroll
    for (int b2 = 0; b2 < 2; ++b2)
      xgv[g][b2] = xg[((size_t)(0 * Bv + eb + 16 * b2) << 12) + g * Hv + u0 + eu];

  for (int tl = 0; tl < Tc; ++tl) {
    int t = t0 + tl;
    const u32x4* hr = (const u32x4*)(hAv + (size_t)(t & 1) * 32768);
    u32 ee = ((u32)(t & 0xffff) << 16) | (u32)(t & 0xffff);  // expected epoch pair

    floatx16 acc0, acc1;
#pragma unroll
    for (int r = 0; r < 16; ++r) { acc0[r] = 0.f; acc1[r] = 0.f; }

    // issue ALL 32 sc1 loads up-front (4 groups x 8); counted vmcnt per group
    u32x4 vb[4][8];
#pragma unroll
    for (int g = 0; g < 4; ++g) {
#pragma unroll
      for (int q = 0; q < 4; ++q) {
        int kt = (kh << 4) + (g << 2) + q;
        const u32x4* p = hr + (((size_t)((kt << 6) + lane)) << 1);
        vb[g][2 * q]     = ld16_sc1(p);
        vb[g][2 * q + 1] = ld16_sc1(p + 1);
      }
    }

#pragma unroll
    for (int g = 0; g < 4; ++g) {
      if (g == 0)      asm volatile("s_waitcnt vmcnt(24)" ::: "memory");
      else if (g == 1) asm volatile("s_waitcnt vmcnt(16)" ::: "memory");
      else if (g == 2) asm volatile("s_waitcnt vmcnt(8)" ::: "memory");
      else             asm volatile("s_waitcnt vmcnt(0)" ::: "memory");
      __builtin_amdgcn_sched_barrier(0);

      for (;;) {
        int ok = 1;
#pragma unroll
        for (int i = 0; i < 8; ++i) {
          u32x4 w = vb[g][i];
          ok &= (permb(w.x, w.y, 0x03020706u) == ee);  // ep0|ep1<<16
          ok &= (permb(w.z, w.w, 0x03020706u) == ee);
        }
        if (__all(ok)) break;
        // stale: reload this group from LLC
#pragma unroll
        for (int q = 0; q < 4; ++q) {
          int kt = (kh << 4) + (g << 2) + q;
          const u32x4* p = hr + (((size_t)((kt << 6) + lane)) << 1);
          vb[g][2 * q]     = ld16_sc1(p);
          vb[g][2 * q + 1] = ld16_sc1(p + 1);
        }
        asm volatile("s_waitcnt vmcnt(0)" ::: "memory");
        __builtin_amdgcn_sched_barrier(0);
      }

      // pack low halves -> bf16x8 fragments and accumulate
#pragma unroll
      for (int q = 0; q < 4; ++q) {
        u32x4 lo = vb[g][2 * q], hi2 = vb[g][2 * q + 1];
        u32x4 f;
        f.x = permb(lo.x,  lo.y,  0x01000504u);  // h_even | h_odd<<16
        f.y = permb(lo.z,  lo.w,  0x01000504u);
        f.z = permb(hi2.x, hi2.y, 0x01000504u);
        f.w = permb(hi2.z, hi2.w, 0x01000504u);
        union { u32x4 u; bf16x8 b; } cv; cv.u = f;
        int kk = (g << 2) + q;
        acc0 = mfma32(cv.b, w0[kk], acc0);
        acc1 = mfma32(cv.b, w1[kk], acc1);
      }
    }

    // write k-partials, XOR-swizzled: lanes {n,n+8,n+16,n+24} were a 4-way
    // bank conflict at stride 36; key=((n>>3)&3)<<2 spreads them. Reads undo
    // the XOR with the same row-derived key.
    {
      int n = lane & 31;
      int bq = 4 * (lane >> 5);
      int key = ((n >> 3) & 3) << 2;
#pragma unroll
      for (int rq = 0; rq < 4; ++rq) {
        float4 v0 = make_float4(acc0[rq * 4 + 0], acc0[rq * 4 + 1], acc0[rq * 4 + 2], acc0[rq * 4 + 3]);
        float4 v1 = make_float4(acc1[rq * 4 + 0], acc1[rq * 4 + 1], acc1[rq * 4 + 2], acc1[rq * 4 + 3]);
        *(float4*)&red[t & 1][kh][n][(8 * rq + bq) ^ key]      = v0;
        *(float4*)&red[t & 1][kh][32 + n][(8 * rq + bq) ^ key] = v1;
      }
    }

    // next step's xg prefetch: issued before S1, consumed next epilogue;
    // drains harmlessly inside next iter's vmcnt(24).
    float xgn[4][2];
    {
      int tln = (tl + 1 < Tc) ? tl + 1 : tl;
#pragma unroll
      for (int g = 0; g < 4; ++g)
#pragma unroll
        for (int b2 = 0; b2 < 2; ++b2)
          xgn[g][b2] = xg[((size_t)(tln * Bv + eb + 16 * b2) << 12) + g * Hv + u0 + eu];
    }

    __syncthreads();   // S1: the only barrier per step

    // epilogue: thread -> (eu, eb) and (eu, eb+16)
    float hv0, hv1;
    {
      float gs[4][2];
#pragma unroll
      for (int g = 0; g < 4; ++g) {
        int r = g * 16 + eu;
        int keyr = ((r >> 3) & 3) << 2;
#pragma unroll
        for (int b2 = 0; b2 < 2; ++b2) {
          int b = (eb + 16 * b2) ^ keyr;
          gs[g][b2] = red[t & 1][0][r][b] + red[t & 1][1][r][b] +
                      red[t & 1][2][r][b] + red[t & 1][3][r][b] + xgv[g][b2];
        }
      }
      float i0 = 1.f / (1.f + __expf(-gs[0][0]));
      float f0 = 1.f / (1.f + __expf(-gs[1][0]));
      float g0 = 1.f - 2.f / (__expf(2.f * gs[2][0]) + 1.f);
      float o0 = 1.f / (1.f + __expf(-gs[3][0]));
      c0 = f0 * c0 + i0 * g0;
      hv0 = o0 * (1.f - 2.f / (__expf(2.f * c0) + 1.f));

      float i1 = 1.f / (1.f + __expf(-gs[0][1]));
      float f1 = 1.f / (1.f + __expf(-gs[1][1]));
      float g1 = 1.f - 2.f / (__expf(2.f * gs[2][1]) + 1.f);
      float o1 = 1.f / (1.f + __expf(-gs[3][1]));
      c1 = f1 * c1 + i1 * g1;
      hv1 = o1 * (1.f - 2.f / (__expf(2.f * c1) + 1.f));
    }

    // stash out values in LDS (flushed every 16 steps; own addresses only)
    {
      int ts = tl & 15;
      obuf[ts][0][eb][eu] = hv0;
      obuf[ts][1][eb][eu] = hv1;
    }

    // publish h: tagged fire-and-forget stores. No drain, no barrier, no flag.
    {
      u32* hw = hAv + (size_t)((t + 1) & 1) * 32768;
      u32 tg = ((u32)((t + 1) & 0xffff)) << 16;
      st_agent_u32(hw + (((size_t)((bl << 6) + eb +      ((eu >> 3) << 5)) << 3) + (eu & 7)), tg | (u32)f2bf(hv0));
      st_agent_u32(hw + (((size_t)((bl << 6) + eb + 16 + ((eu >> 3) << 5)) << 3) + (eu & 7)), tg | (u32)f2bf(hv1));
    }

    // out flush once per 16 steps (burst drains inside a later vmcnt(24))
    if ((tl & 15) == 15 || tl == Tc - 1) {
      int ns = (tl & 15) + 1;
      int tb = t - (tl & 15);
      for (int ts = 0; ts < ns; ++ts) {
        out[((size_t)(eb * Tv + tb + ts) << 10) + u0 + eu]        = obuf[ts][0][eb][eu];
        out[((size_t)((eb + 16) * Tv + tb + ts) << 10) + u0 + eu] = obuf[ts][1][eb][eu];
      }
    }

#pragma unroll
    for (int g = 0; g < 4; ++g)
#pragma unroll
      for (int b2 = 0; b2 < 2; ++b2) xgv[g][b2] = xgn[g][b2];
  }
  cbuf[eb * Hv + u0 + eu] = c0;
  cbuf[(eb + 16) * Hv + u0 + eu] = c1;
}

extern "C" void kernel_launch(void* const* d_in, const int* in_sizes, int n_in,
                              void* d_out, int out_size, void* d_ws, size_t ws_size,
                              hipStream_t stream) {
  const float* x  = (const float*)d_in[0];
  const float* Wx = (const float*)d_in[1];
  const float* bx = (const float*)d_in[2];
  const float* Wh = (const float*)d_in[3];
  const float* bh = (const float*)d_in[4];
  float* out = (float*)d_out;
  char* ws = (char*)d_ws;

  // ws layout
  u32*   hAv = (u32*)(ws + 4096);                          // 256 KB (2 x 128KB, tagged u32)
  float* cb  = (float*)(ws + 4096 + (256 << 10));          // 128 KB
  u16*   xb  = (u16*)(ws + 4096 + (384 << 10));            // 16 MB
  u16*   wxb = xb + (size_t)Bv * Tv * Iv;                  // 4 MB
  u16*   whf = wxb + (size_t)NG * Iv;                      // 8 MB
  float* xg  = (float*)(whf + (size_t)64 * 2 * 64 * 64 * 8);

  size_t fixedB = 4096 + (384ull << 10) +
                  ((size_t)Bv * Tv * Iv + (size_t)NG * Iv + (size_t)64 * 2 * 64 * 64 * 8) * 2;
  int tcshift = 9;
  while (tcshift > 2 && fixedB + (((size_t)Bv * NG * 4) << tcshift) > ws_size) --tcshift;
  int Tc = 1 << tcshift;

  k_init<<<260, 256, 0, stream>>>((unsigned int*)ws, (4096 + (256 << 10)) / 4);
  k_f2bf<<<(Bv * Tv * Iv) / 256, 256, 0, stream>>>(x, xb, Bv * Tv * Iv);
  k_f2bf<<<(NG * Iv) / 256, 256, 0, stream>>>(Wx, wxb, NG * Iv);
  k_whf<<<2048, 256, 0, stream>>>(Wh, whf);

  for (int t0 = 0; t0 < Tv; t0 += Tc) {
    k_xg<<<dim3(Tc / 4, 32), 256, 0, stream>>>(xb, wxb, bx, bh, xg, t0, tcshift);
    k_scan<<<64, 256, 0, stream>>>(whf, xg, hAv, cb, out, t0, Tc);
  }
}

// Round 9
// 2396.464 us; speedup vs baseline: 1.1613x; 1.1613x over previous
//
#include <hip/hip_runtime.h>
#include <hip/hip_bf16.h>

#define Bv 32
#define Tv 512
#define Iv 512
#define Hv 1024
#define NG 4096  // 4*H

typedef short bf16x8 __attribute__((ext_vector_type(8)));   // 8 bf16 held as i16 (guide §3)
typedef float floatx16 __attribute__((ext_vector_type(16)));
typedef unsigned short u16;
typedef unsigned int u32;
typedef unsigned long long u64;
typedef u32 u32x4 __attribute__((ext_vector_type(4)));

__device__ __forceinline__ u16 f2bf(float f) {
  __hip_bfloat16 h = __float2bfloat16(f);
  return *reinterpret_cast<u16*>(&h);
}

__device__ __forceinline__ floatx16 mfma32(bf16x8 a, bf16x8 b, floatx16 c) {
  return __builtin_amdgcn_mfma_f32_32x32x16_bf16(a, b, c, 0, 0, 0);
}

__device__ __forceinline__ bf16x8 as_bf16x8(u32x4 v) {
  union { u32x4 u; bf16x8 b; } c; c.u = v; return c.b;
}

// relaxed agent-scope accesses: lower to global_load/store with sc1 (LLC-direct,
// bypass non-coherent per-XCD L2). No cache-maintenance instructions emitted.
__device__ __forceinline__ u64 ld_agent_u64(const u64* p) {
  return __hip_atomic_load(p, __ATOMIC_RELAXED, __HIP_MEMORY_SCOPE_AGENT);
}
__device__ __forceinline__ void st_agent_u16(u16* p, u16 v) {
  __hip_atomic_store(p, v, __ATOMIC_RELAXED, __HIP_MEMORY_SCOPE_AGENT);
}

__device__ __forceinline__ bf16x8 mk_frag(u64 lo, u64 hi) {
  union { u64 q[2]; bf16x8 v; } u;
  u.q[0] = lo; u.q[1] = hi;
  return u.v;
}

// ---------------- init: zero arrival region (4KB) + hA double buffer (128KB)
__global__ void k_init(unsigned int* p, int n) {
  int i = blockIdx.x * blockDim.x + threadIdx.x;
  if (i < n) p[i] = 0u;
}

// ---------------- elementwise fp32 -> bf16
__global__ void k_f2bf(const float* __restrict__ in, u16* __restrict__ out, int n) {
  int i = blockIdx.x * blockDim.x + threadIdx.x;
  if (i < n) out[i] = f2bf(in[i]);
}

// ---------------- gather Wh into B-fragment layout: WhF[bl(64)][nt(2)][kt(64)][lane(64)][8]
__global__ void k_whf(const float* __restrict__ Wh, u16* __restrict__ whf) {
  int tid = blockIdx.x * 256 + threadIdx.x;   // 2048*256 = 524288
  int lane = tid & 63;
  int kt   = (tid >> 6) & 63;
  int nt   = (tid >> 12) & 1;
  int bl   = tid >> 13;
  int r    = nt * 32 + (lane & 31);
  int gate = r >> 4, du = r & 15;
  int row  = gate * Hv + bl * 16 + du;
  int k0   = kt * 16 + (lane >> 5) * 8;
  const float* s = Wh + (size_t)row * Hv + k0;
  u16* d = whf + (size_t)tid * 8;
#pragma unroll
  for (int j = 0; j < 8; ++j) d[j] = f2bf(s[j]);
}

// ---------------- xg GEMM (unchanged)
__global__ __launch_bounds__(256) void k_xg(const u16* __restrict__ xb, const u16* __restrict__ wxb,
                                            const float* __restrict__ bx, const float* __restrict__ bh,
                                            float* __restrict__ xg, int t0, int tcshift) {
  __shared__ u16 Al[128 * 40];
  __shared__ u16 Bl[128 * 40];
  int tid = threadIdx.x;
  int wave = tid >> 6, lane = tid & 63;
  int wm = wave & 1, wn = wave >> 1;
  int bm = blockIdx.x, bn = blockIdx.y;
  int Tc = 1 << tcshift;

  floatx16 acc[2][2];
#pragma unroll
  for (int a = 0; a < 2; ++a)
#pragma unroll
    for (int c = 0; c < 2; ++c)
#pragma unroll
      for (int r = 0; r < 16; ++r) acc[a][c][r] = 0.f;

  int lr = tid >> 1;
  int lk = (tid & 1) * 16;
  int m  = bm * 128 + lr;
  int b  = m >> tcshift;
  int tl = m & (Tc - 1);
  const u16* asrc = xb + (size_t)(b * Tv + t0 + tl) * Iv + lk;
  int nrow = bn * 128 + lr;
  const u16* bsrc = wxb + (size_t)nrow * Iv + lk;
  u16* adst = &Al[lr * 40 + lk];
  u16* bdst = &Bl[lr * 40 + lk];

  for (int k0 = 0; k0 < Iv; k0 += 32) {
    __syncthreads();
    *(uint4*)adst       = *(const uint4*)(asrc);
    *(uint4*)(adst + 8) = *(const uint4*)(asrc + 8);
    *(uint4*)bdst       = *(const uint4*)(bsrc);
    *(uint4*)(bdst + 8) = *(const uint4*)(bsrc + 8);
    asrc += 32; bsrc += 32;
    __syncthreads();
#pragma unroll
    for (int kt = 0; kt < 2; ++kt) {
      int ko = kt * 16 + (lane >> 5) * 8;
      bf16x8 a0 = *(const bf16x8*)(&Al[(wm * 64 +      (lane & 31)) * 40 + ko]);
      bf16x8 a1 = *(const bf16x8*)(&Al[(wm * 64 + 32 + (lane & 31)) * 40 + ko]);
      bf16x8 b0 = *(const bf16x8*)(&Bl[(wn * 64 +      (lane & 31)) * 40 + ko]);
      bf16x8 b1 = *(const bf16x8*)(&Bl[(wn * 64 + 32 + (lane & 31)) * 40 + ko]);
      acc[0][0] = mfma32(a0, b0, acc[0][0]);
      acc[0][1] = mfma32(a0, b1, acc[0][1]);
      acc[1][0] = mfma32(a1, b0, acc[1][0]);
      acc[1][1] = mfma32(a1, b1, acc[1][1]);
    }
  }
#pragma unroll
  for (int mt = 0; mt < 2; ++mt) {
#pragma unroll
    for (int ntt = 0; ntt < 2; ++ntt) {
      int nGl = bn * 128 + wn * 64 + ntt * 32 + (lane & 31);
      float bias = bx[nGl] + bh[nGl];
#pragma unroll
      for (int r = 0; r < 16; ++r) {
        int mrow = (r & 3) + 8 * (r >> 2) + 4 * (lane >> 5);
        int mG = bm * 128 + wm * 64 + mt * 32 + mrow;
        int bb = mG >> tcshift;
        int tt = mG & (Tc - 1);
        xg[((size_t)(tt * Bv + bb) << 12) + nGl] = acc[mt][ntt][r] + bias;
      }
    }
  }
}

// ---------------- persistent scan: 64 blocks x 256 thr (R4 structure, proven)
// Sync: per-block publish flag + per-wave release poll.
//  - publish: one tid0 store to arrivals[bl*16] after vmcnt(0)+S2 (all the
//    block's hA stores drained).
//  - release: wave kh polls the 16 flags of blocks 16kh..16kh+15 (its kt
//    producers) and proceeds straight into its hA loads.
//  - poll hygiene: xg prefetch issued at the TOP of the step; out values
//    stash in LDS, flushed once per 16 steps after publish.
// THIS ROUND'S ONLY DELTA vs the round-4 passing kernel: weights are pinned
// in 128 VGPRs via asm-volatile loads (outputs can't be rematerialized), so
// the compiler cannot re-fetch 2KB/thread of weights from cache every step
// (R4's VGPR_Count=132 proved it was doing exactly that). LDS (106KB) already
// limits to 1 block/CU, and launch_bounds(256,1) allows ~512 VGPRs/wave, so
// the pinning costs no occupancy. No manual vmcnt counting anywhere (R8's
// failure mode: spill traffic breaks hand-counted vmcnt).
// Safety: identical ordering argument to R4.
__global__ __launch_bounds__(256, 1) void k_scan(const u16* __restrict__ whf, const float* __restrict__ xg,
                                                 u64* __restrict__ hA, float* __restrict__ cbuf,
                                                 float* __restrict__ out, int* arrivals, int t0, int Tc) {
  __shared__ float red[2][4][64][36];      // [parity][kh][gate-row][batch], 73728 B
  __shared__ float obuf[16][2][16][16];    // [ts][b2][eb][eu] out stash, 32768 B
  int tid = threadIdx.x;
  int bl = blockIdx.x;                  // 0..63, owns units u0..u0+15
  int kh = tid >> 6, lane = tid & 63;   // wave = k-quarter
  int eu = tid & 15, eb = tid >> 4;     // epilogue: unit-in-block, batch 0..15 (+16)
  int u0 = bl * 16;

  // ---- weights pinned in 128 VGPRs: w[kk]=nt0, w[16+kk]=nt1 for kt=kh*16+kk
  u32x4 w[32];
  {
    const u16* wb0 = whf + ((size_t)(bl * 2 + 0) << 15);
    const u16* wb1 = whf + ((size_t)(bl * 2 + 1) << 15);
#pragma unroll
    for (int kk = 0; kk < 16; ++kk) {
      int kt = kh * 16 + kk;
      asm volatile("global_load_dwordx4 %0, %1, off" : "=v"(w[kk])
                   : "v"(wb0 + (size_t)((kt << 6) + lane) * 8));
      asm volatile("global_load_dwordx4 %0, %1, off" : "=v"(w[kk + 16])
                   : "v"(wb1 + (size_t)((kt << 6) + lane) * 8));
    }
    asm volatile("s_waitcnt vmcnt(0)" ::: "memory");
    __builtin_amdgcn_sched_barrier(0);
  }

  float c0, c1;
  if (t0 == 0) { c0 = 0.f; c1 = 0.f; }
  else {
    c0 = cbuf[eb * Hv + u0 + eu];
    c1 = cbuf[(eb + 16) * Hv + u0 + eu];
  }

  u16* hA16 = (u16*)hA;
  // wave's poll slot: 4 lanes share each of the 16 producer flags
  const int* fp = arrivals + ((kh << 4) + (lane & 15)) * 16;

  // xg prefetch for tl=0
  float xgv[4][2];
#pragma unroll
  for (int g = 0; g < 4; ++g)
#pragma unroll
    for (int b2 = 0; b2 < 2; ++b2)
      xgv[g][b2] = xg[((size_t)(0 * Bv + eb + 16 * b2) << 12) + g * Hv + u0 + eu];

  for (int tl = 0; tl < Tc; ++tl) {
    int t = t0 + tl;

    // per-wave release: my 16 producers (all their waves drained before publish)
    while (__hip_atomic_load(fp, __ATOMIC_RELAXED, __HIP_MEMORY_SCOPE_AGENT) < t) { }
    asm volatile("" ::: "memory");

    const u64* hAr = hA + (size_t)(t & 1) * 8192;  // read buffer (8192 u64 each)

    // hoist all 32 LLC loads; latency paid once (compiler manages waitcnts)
    u64 alo[16], ahi[16];
#pragma unroll
    for (int kk = 0; kk < 16; ++kk) {
      size_t fi = (size_t)((((kh << 4) + kk) << 6) + lane) * 2;
      alo[kk] = ld_agent_u64(hAr + fi);
      ahi[kk] = ld_agent_u64(hAr + fi + 1);
    }

    // xg prefetch for NEXT step, issued early: completes under MFMA+epilogue,
    // so later poll probes' implicit vmcnt(0) never wait on it.
    float xgn[4][2];
    {
      int tln = (tl + 1 < Tc) ? tl + 1 : tl;
#pragma unroll
      for (int g = 0; g < 4; ++g)
#pragma unroll
        for (int b2 = 0; b2 < 2; ++b2)
          xgn[g][b2] = xg[((size_t)(tln * Bv + eb + 16 * b2) << 12) + g * Hv + u0 + eu];
    }

    floatx16 acc0, acc1;
#pragma unroll
    for (int r = 0; r < 16; ++r) { acc0[r] = 0.f; acc1[r] = 0.f; }
#pragma unroll
    for (int kk = 0; kk < 16; ++kk) {
      bf16x8 a = mk_frag(alo[kk], ahi[kk]);
      acc0 = mfma32(a, as_bf16x8(w[kk]),      acc0);
      acc1 = mfma32(a, as_bf16x8(w[kk + 16]), acc1);
    }

    // write k-partials: row = nt*32 + (lane&31); b = (r&3) + 8*(r>>2) + 4*(lane>>5)
    {
      int n = lane & 31;
      int bq = 4 * (lane >> 5);
#pragma unroll
      for (int rq = 0; rq < 4; ++rq) {
        float4 v0 = make_float4(acc0[rq * 4 + 0], acc0[rq * 4 + 1], acc0[rq * 4 + 2], acc0[rq * 4 + 3]);
        float4 v1 = make_float4(acc1[rq * 4 + 0], acc1[rq * 4 + 1], acc1[rq * 4 + 2], acc1[rq * 4 + 3]);
        *(float4*)&red[t & 1][kh][n][8 * rq + bq]      = v0;
        *(float4*)&red[t & 1][kh][32 + n][8 * rq + bq] = v1;
      }
    }

    __syncthreads();   // S1: join waves for the cross-wave reduce

    // epilogue: thread -> (eu, eb) and (eu, eb+16)
    float hv0, hv1;
    {
      float gs[4][2];
#pragma unroll
      for (int g = 0; g < 4; ++g) {
        int r = g * 16 + eu;
#pragma unroll
        for (int b2 = 0; b2 < 2; ++b2) {
          int b = eb + 16 * b2;
          gs[g][b2] = red[t & 1][0][r][b] + red[t & 1][1][r][b] +
                      red[t & 1][2][r][b] + red[t & 1][3][r][b] + xgv[g][b2];
        }
      }
      float i0 = 1.f / (1.f + __expf(-gs[0][0]));
      float f0 = 1.f / (1.f + __expf(-gs[1][0]));
      float g0 = 1.f - 2.f / (__expf(2.f * gs[2][0]) + 1.f);
      float o0 = 1.f / (1.f + __expf(-gs[3][0]));
      c0 = f0 * c0 + i0 * g0;
      hv0 = o0 * (1.f - 2.f / (__expf(2.f * c0) + 1.f));

      float i1 = 1.f / (1.f + __expf(-gs[0][1]));
      float f1 = 1.f / (1.f + __expf(-gs[1][1]));
      float g1 = 1.f - 2.f / (__expf(2.f * gs[2][1]) + 1.f);
      float o1 = 1.f / (1.f + __expf(-gs[3][1]));
      c1 = f1 * c1 + i1 * g1;
      hv1 = o1 * (1.f - 2.f / (__expf(2.f * c1) + 1.f));
    }

    // stash out values in LDS (flushed every 16 steps, off the poll path)
    {
      int ts = tl & 15;
      obuf[ts][0][eb][eu] = hv0;
      obuf[ts][1][eb][eu] = hv1;
    }

    // publish h: only the two hA stores sit before the drain
    u16* hAw16 = hA16 + (size_t)((t + 1) & 1) * 32768;
    st_agent_u16(hAw16 + ((size_t)((bl << 6) + eb +      ((eu >> 3) << 5)) << 3) + (eu & 7), f2bf(hv0));
    st_agent_u16(hAw16 + ((size_t)((bl << 6) + eb + 16 + ((eu >> 3) << 5)) << 3) + (eu & 7), f2bf(hv1));
    asm volatile("s_waitcnt vmcnt(0)" ::: "memory");
    __syncthreads();   // S2: whole block's hA stores drained

    // arrival: plain store, own 64B slot — no RMW chain
    if (tid == 0)
      __hip_atomic_store(arrivals + bl * 16, t + 1, __ATOMIC_RELAXED, __HIP_MEMORY_SCOPE_AGENT);

    // out flush once per 16 steps (burst overlaps the next poll window)
    if ((tl & 15) == 15 || tl == Tc - 1) {
      int ns = (tl & 15) + 1;
      int tb = t - (tl & 15);
      for (int ts = 0; ts < ns; ++ts) {
        out[((size_t)(eb * Tv + tb + ts) << 10) + u0 + eu]        = obuf[ts][0][eb][eu];
        out[((size_t)((eb + 16) * Tv + tb + ts) << 10) + u0 + eu] = obuf[ts][1][eb][eu];
      }
    }

#pragma unroll
    for (int g = 0; g < 4; ++g)
#pragma unroll
      for (int b2 = 0; b2 < 2; ++b2) xgv[g][b2] = xgn[g][b2];
  }
  cbuf[eb * Hv + u0 + eu] = c0;
  cbuf[(eb + 16) * Hv + u0 + eu] = c1;
}

extern "C" void kernel_launch(void* const* d_in, const int* in_sizes, int n_in,
                              void* d_out, int out_size, void* d_ws, size_t ws_size,
                              hipStream_t stream) {
  const float* x  = (const float*)d_in[0];
  const float* Wx = (const float*)d_in[1];
  const float* bx = (const float*)d_in[2];
  const float* Wh = (const float*)d_in[3];
  const float* bh = (const float*)d_in[4];
  float* out = (float*)d_out;
  char* ws = (char*)d_ws;

  // ws layout
  int*   arrivals = (int*)ws;                              // [0, 4KB): 64 arrivals, 64B apart
  u64*   hA  = (u64*)(ws + 4096);                          // 128 KB (2 x 64KB)
  float* cb  = (float*)(ws + 4096 + (128 << 10));          // 128 KB
  u16*   xb  = (u16*)(ws + 4096 + (256 << 10));            // 16 MB
  u16*   wxb = xb + (size_t)Bv * Tv * Iv;                  // 4 MB
  u16*   whf = wxb + (size_t)NG * Iv;                      // 8 MB
  float* xg  = (float*)(whf + (size_t)64 * 2 * 64 * 64 * 8);

  size_t fixedB = 4096 + (256ull << 10) +
                  ((size_t)Bv * Tv * Iv + (size_t)NG * Iv + (size_t)64 * 2 * 64 * 64 * 8) * 2;
  int tcshift = 9;
  while (tcshift > 2 && fixedB + (((size_t)Bv * NG * 4) << tcshift) > ws_size) --tcshift;
  int Tc = 1 << tcshift;

  k_init<<<132, 256, 0, stream>>>((unsigned int*)ws, (4096 + (128 << 10)) / 4);
  k_f2bf<<<(Bv * Tv * Iv) / 256, 256, 0, stream>>>(x, xb, Bv * Tv * Iv);
  k_f2bf<<<(NG * Iv) / 256, 256, 0, stream>>>(Wx, wxb, NG * Iv);
  k_whf<<<2048, 256, 0, stream>>>(Wh, whf);

  for (int t0 = 0; t0 < Tv; t0 += Tc) {
    k_xg<<<dim3(Tc / 4, 32), 256, 0, stream>>>(xb, wxb, bx, bh, xg, t0, tcshift);
    k_scan<<<64, 256, 0, stream>>>(whf, xg, hA, cb, out, arrivals, t0, Tc);
  }
}